// Round 1
// baseline (309.935 us; speedup 1.0000x reference)
//
#include <hip/hip_runtime.h>

#define BSZ 4
#define CIN 64
#define HH 128
#define WW 128
#define OCH 64
#define HWSZ (HH*WW)
#define KK 9
#define NPIX (BSZ*HH*WW)   // reduction count per channel: 65536

// workspace layout (float offsets)
#define Y_OFF     0
#define WT_OFF    (BSZ*OCH*HWSZ)          // 4194304, size 9*64*64 = 36864
#define WOFFT_OFF (WT_OFF + KK*CIN*OCH)   // size 576*18 = 10368
#define STATS_OFF (WOFFT_OFF + 576*18)    // gsum[64], gsq[64], scale[64], shift[64]

// ---------------- kernel 1: weight pre-transpose ----------------
__global__ void transpose_w(const float* __restrict__ w_def,
                            const float* __restrict__ w_off,
                            float* __restrict__ wt,      // [k][c][oc]
                            float* __restrict__ wofft) { // [c*9+kk][18]
    int i = blockIdx.x * 256 + threadIdx.x;
    if (i < 36864) {
        int oc = i / 576, r = i % 576;
        int c = r / 9, k = r % 9;
        wt[(k * CIN + c) * OCH + oc] = w_def[i];
    } else if (i < 36864 + 10368) {
        int j = i - 36864;
        int oc = j / 576, r = j % 576;
        wofft[r * 18 + oc] = w_off[j];
    }
}

// ---------------- kernel 2: fused offset-conv + deform-conv ----------------
__global__ __launch_bounds__(256, 2) void fused_main(
    const float* __restrict__ x,
    const float* __restrict__ b_off,
    const float* __restrict__ b_def,
    const float* __restrict__ wofft,
    const float* __restrict__ wt,
    float* __restrict__ ybuf,
    float* __restrict__ gsum,
    float* __restrict__ gsq)
{
    __shared__ float off_lds[18][WW];   // 9 KB
    __shared__ float s_lds[CIN][WW];    // 32 KB
    __shared__ float w_lds[CIN][OCH];   // 16 KB

    const int tid = threadIdx.x;
    const int r  = blockIdx.x;
    const int b  = r >> 7;
    const int ho = r & 127;

    // ---- phase 1: 3x3 offset conv for this row (18 channels) ----
    {
        const int wo = tid & 127;
        const int og = __builtin_amdgcn_readfirstlane(tid >> 7); // wave-uniform 0/1
        float oacc[9];
        #pragma unroll
        for (int j = 0; j < 9; ++j) oacc[j] = b_off[og * 9 + j];
        const float* xb = x + b * CIN * HWSZ;
        for (int c = 0; c < CIN; ++c) {
            const float* xc = xb + c * HWSZ;
            #pragma unroll
            for (int kh = 0; kh < 3; ++kh) {
                int yy = ho - 1 + kh;
                int vy = ((unsigned)yy < (unsigned)HH);
                #pragma unroll
                for (int kw = 0; kw < 3; ++kw) {
                    int xx = wo - 1 + kw;
                    float xv = (vy && ((unsigned)xx < (unsigned)WW)) ? xc[yy * WW + xx] : 0.f;
                    const float* wp = wofft + (c * 9 + kh * 3 + kw) * 18 + og * 9; // uniform -> s_load
                    #pragma unroll
                    for (int j = 0; j < 9; ++j) oacc[j] = fmaf(xv, wp[j], oacc[j]);
                }
            }
        }
        #pragma unroll
        for (int j = 0; j < 9; ++j) off_lds[og * 9 + j][wo] = oacc[j];
    }
    __syncthreads();

    // ---- phase 2: per kernel-point sample + matmul ----
    const int wog = tid & 31, ocg = tid >> 5;
    const int wo0 = wog * 4, oc0 = ocg * 8;
    float acc[8][4];
    #pragma unroll
    for (int j = 0; j < 8; ++j)
        #pragma unroll
        for (int i = 0; i < 4; ++i) acc[j][i] = 0.f;

    const int swo = tid & 127;       // sampling pixel
    const int sch = (tid >> 7) * 32; // sampling channel base

    for (int k = 0; k < KK; ++k) {
        __syncthreads();  // previous iteration's readers done before overwrite
        // stage w[k] -> w_lds[c][oc], coalesced float4
        {
            const float4* src = (const float4*)(wt + k * CIN * OCH);
            float4* dst = (float4*)(&w_lds[0][0]);
            #pragma unroll
            for (int m = 0; m < 4; ++m) dst[tid + m * 256] = src[tid + m * 256];
        }
        // bilinear sampling: metadata once per (pixel,k), reuse over 32 channels
        {
            float dy = off_lds[2 * k][swo];
            float dx = off_lds[2 * k + 1][swo];
            float py = (float)(ho - 1 + (k / 3)) + dy;
            float px = (float)(swo - 1 + (k % 3)) + dx;
            float y0f = floorf(py), x0f = floorf(px);
            int y0 = (int)y0f, x0 = (int)x0f;
            float wy1 = py - y0f, wy0 = 1.f - wy1;
            float wx1 = px - x0f, wx0 = 1.f - wx1;
            int vy0 = ((unsigned)y0 < (unsigned)HH), vy1 = ((unsigned)(y0 + 1) < (unsigned)HH);
            int vx0 = ((unsigned)x0 < (unsigned)WW), vx1 = ((unsigned)(x0 + 1) < (unsigned)WW);
            float w00 = wy0 * wx0 * (float)(vy0 & vx0);
            float w01 = wy0 * wx1 * (float)(vy0 & vx1);
            float w10 = wy1 * wx0 * (float)(vy1 & vx0);
            float w11 = wy1 * wx1 * (float)(vy1 & vx1);
            int y0c = min(max(y0, 0), HH - 1), y1c = min(max(y0 + 1, 0), HH - 1);
            int x0c = min(max(x0, 0), WW - 1), x1c = min(max(x0 + 1, 0), WW - 1);
            int i00 = y0c * WW + x0c, i01 = y0c * WW + x1c;
            int i10 = y1c * WW + x0c, i11 = y1c * WW + x1c;
            const float* xc = x + (b * CIN + sch) * HWSZ;
            #pragma unroll 8
            for (int cc = 0; cc < 32; ++cc) {
                float v = xc[i00] * w00;
                v = fmaf(xc[i01], w01, v);
                v = fmaf(xc[i10], w10, v);
                v = fmaf(xc[i11], w11, v);
                s_lds[sch + cc][swo] = v;
                xc += HWSZ;
            }
        }
        __syncthreads();
        // register-tiled matmul: 8 oc x 4 wo per thread
        #pragma unroll 8
        for (int c = 0; c < CIN; ++c) {
            float4 s4 = *(const float4*)&s_lds[c][wo0];
            float4 wa = *(const float4*)&w_lds[c][oc0];
            float4 wb = *(const float4*)&w_lds[c][oc0 + 4];
            float wreg[8] = {wa.x, wa.y, wa.z, wa.w, wb.x, wb.y, wb.z, wb.w};
            float sreg[4] = {s4.x, s4.y, s4.z, s4.w};
            #pragma unroll
            for (int j = 0; j < 8; ++j)
                #pragma unroll
                for (int i = 0; i < 4; ++i)
                    acc[j][i] = fmaf(wreg[j], sreg[i], acc[j][i]);
        }
    }

    // ---- epilogue: bias, store y, per-channel stats ----
    float lsum[8], lsq[8];
    const int ybase = b * OCH * HWSZ + ho * WW;
    #pragma unroll
    for (int j = 0; j < 8; ++j) {
        int oc = oc0 + j;
        float bd = b_def[oc];
        float4 v;
        v.x = acc[j][0] + bd;
        v.y = acc[j][1] + bd;
        v.z = acc[j][2] + bd;
        v.w = acc[j][3] + bd;
        *(float4*)&ybuf[ybase + oc * HWSZ + wo0] = v;
        lsum[j] = v.x + v.y + v.z + v.w;
        lsq[j] = v.x * v.x + v.y * v.y + v.z * v.z + v.w * v.w;
    }
    // half-wave (32-lane) butterfly: threads sharing ocg are one half-wave
    #pragma unroll
    for (int m = 1; m <= 16; m <<= 1) {
        #pragma unroll
        for (int j = 0; j < 8; ++j) {
            lsum[j] += __shfl_xor(lsum[j], m);
            lsq[j]  += __shfl_xor(lsq[j], m);
        }
    }
    if ((tid & 31) == 0) {
        #pragma unroll
        for (int j = 0; j < 8; ++j) {
            atomicAdd(&gsum[oc0 + j], lsum[j]);
            atomicAdd(&gsq[oc0 + j],  lsq[j]);
        }
    }
}

// ---------------- kernel 3: BN stats finalize ----------------
__global__ void finalize_bn(const float* __restrict__ gsum, const float* __restrict__ gsq,
                            const float* __restrict__ gamma, const float* __restrict__ beta,
                            float* __restrict__ ss) {
    int c = threadIdx.x;
    if (c < OCH) {
        const float inv = 1.f / (float)NPIX;
        float mean = gsum[c] * inv;
        float var = gsq[c] * inv - mean * mean;
        float rstd = rsqrtf(var + 1e-5f);
        float sc = gamma[c] * rstd;
        ss[c] = sc;
        ss[OCH + c] = beta[c] - mean * sc;
    }
}

// ---------------- kernel 4: BN apply + PReLU ----------------
__global__ __launch_bounds__(256) void apply_bn(const float* __restrict__ ybuf,
                                                const float* __restrict__ ss,
                                                const float* __restrict__ prelu,
                                                float* __restrict__ out) {
    int i = blockIdx.x * 256 + threadIdx.x;       // float4 index, exact grid
    int oc = ((i * 4) >> 14) & 63;
    float sc = ss[oc], sh = ss[OCH + oc], pw = prelu[oc];
    float4 v = ((const float4*)ybuf)[i];
    float t;
    t = fmaf(v.x, sc, sh); v.x = t >= 0.f ? t : pw * t;
    t = fmaf(v.y, sc, sh); v.y = t >= 0.f ? t : pw * t;
    t = fmaf(v.z, sc, sh); v.z = t >= 0.f ? t : pw * t;
    t = fmaf(v.w, sc, sh); v.w = t >= 0.f ? t : pw * t;
    ((float4*)out)[i] = v;
}

extern "C" void kernel_launch(void* const* d_in, const int* in_sizes, int n_in,
                              void* d_out, int out_size, void* d_ws, size_t ws_size,
                              hipStream_t stream) {
    const float* x      = (const float*)d_in[0];
    const float* w_off  = (const float*)d_in[1];
    const float* b_off  = (const float*)d_in[2];
    const float* w_def  = (const float*)d_in[3];
    const float* b_def  = (const float*)d_in[4];
    const float* gamma  = (const float*)d_in[5];
    const float* beta   = (const float*)d_in[6];
    const float* prelu  = (const float*)d_in[7];

    float* ws    = (float*)d_ws;
    float* ybuf  = ws + Y_OFF;
    float* wt    = ws + WT_OFF;
    float* wofft = ws + WOFFT_OFF;
    float* stats = ws + STATS_OFF;
    float* gsum  = stats;
    float* gsq   = stats + OCH;
    float* ss    = stats + 2 * OCH;

    hipMemsetAsync(stats, 0, 2 * OCH * sizeof(float), stream);
    transpose_w<<<185, 256, 0, stream>>>(w_def, w_off, wt, wofft);
    fused_main<<<BSZ * HH, 256, 0, stream>>>(x, b_off, b_def, wofft, wt, ybuf, gsum, gsq);
    finalize_bn<<<1, 64, 0, stream>>>(gsum, gsq, gamma, beta, ss);
    apply_bn<<<(BSZ * OCH * HWSZ) / 4 / 256, 256, 0, stream>>>(ybuf, ss, prelu, (float*)d_out);
}